// Round 5
// baseline (247.373 us; speedup 1.0000x reference)
//
#include <hip/hip_runtime.h>
#include <hip/hip_bf16.h>

// (B, LIN, E, D, N) = (32, 2048, 512, 512, 2)
#define L_SZ 2048
#define E_SZ 512
#define D_SZ 512
#define ND   1024
// ws layout: dec_proj (32*512 f32) | Bt (512*512 bf16, [n][k]) | spart (2*32*2048 f32)
#define WS_DEC_OFF 0
#define WS_BT_OFF  (32*512*4)
#define WS_SP_OFF  (32*512*4 + 512*512*2)

typedef unsigned short ushort_t;
typedef unsigned int   uint_t;
typedef __attribute__((ext_vector_type(8))) short short8;   // 8 bf16 (MFMA A/B frag)
typedef __attribute__((ext_vector_type(4))) float floatx4;  // MFMA C/D frag

__device__ __forceinline__ ushort_t f2bf(float f) {
  uint_t u = __builtin_bit_cast(uint_t, f);
  u += 0x7fffu + ((u >> 16) & 1u);
  return (ushort_t)(u >> 16);
}

__device__ __forceinline__ float fast_tanh(float x) {
  float e = __expf(2.0f * x);
  return 1.0f - 2.0f * __builtin_amdgcn_rcpf(e + 1.0f);
}

// async 16B/lane global->LDS DMA; lds dest wave-uniform, HW deposits lane i at +16i
__device__ __forceinline__ void dma16(const ushort_t* g, ushort_t* l) {
  __builtin_amdgcn_global_load_lds(
      (const __attribute__((address_space(1))) uint_t*)(const void*)g,
      (__attribute__((address_space(3))) uint_t*)(void*)l,
      16, 0, 0);
}

// ---------------------------------------------------------------------------
// Prep (verbatim round-2 PROVEN): 512 blocks
//  0..255  : dec_proj[b][d], k split 4-way across waves + LDS reduce
//  256..511: Bt[n][k] = bf16(W1[1024+k][n]) via 32x32 LDS transpose tiles
// ---------------------------------------------------------------------------
__global__ __launch_bounds__(256) void prep_k(const float* __restrict__ dh,
                                              const float* __restrict__ W1,
                                              const float* __restrict__ b1,
                                              float* __restrict__ dec,
                                              ushort_t* __restrict__ Bt) {
  int blk = blockIdx.x, t = threadIdx.x;
  if (blk < 256) {
    int b = blk >> 3, d = (blk & 7) * 64 + (t & 63);
    int q = t >> 6;
    __shared__ float red[4][64];
    const float* dfb = dh + b * ND;
    float s = 0.f;
    #pragma unroll 8
    for (int k = q * 256; k < q * 256 + 256; k++)
      s = fmaf(dfb[k], W1[k * D_SZ + d], s);
    red[q][t & 63] = s;
    __syncthreads();
    if (q == 0)
      dec[b * D_SZ + d] = red[0][t] + red[1][t] + red[2][t] + red[3][t] + b1[d];
  } else {
    int tid = blk - 256;
    int tk = (tid >> 4) * 32, tn = (tid & 15) * 32;
    __shared__ float tile[32][33];
    int cc = t & 31, r8 = t >> 5;
    #pragma unroll
    for (int p = 0; p < 4; p++) {
      int r = r8 + p * 8;
      tile[r][cc] = W1[(ND + tk + r) * D_SZ + tn + cc];
    }
    __syncthreads();
    #pragma unroll
    for (int p = 0; p < 4; p++) {
      int nn = r8 + p * 8;
      Bt[(tn + nn) * E_SZ + tk + cc] = f2bf(tile[cc][nn]);
    }
  }
}

// ---------------------------------------------------------------------------
// Main: ROUND-2 PROVEN two-barrier schedule; only the tile shape changed.
// WG = 256 threads (4 waves) = 64 rows x 256 cols (n-half nh=blockIdx.z).
// K = 512 in 8 windows of BK=64. Per window:
//   barrier1 -> stage A (2 chunks/thread, reg->bf16->ds_write) + issue 8 B-DMAs
//   barrier2 (drains) -> prefetch next-A regs -> 2 k-steps x (4mt x 4nt) MFMA.
// Wave w owns cols nh*256 + w*64 .. +64: acc[4][4] = 64 AGPRs.
// LDS = As 8 KB + Bs 32 KB = 40 KB; regs <= 128 -> target 3-4 WGs/CU
// (3-4 independent barrier groups per CU hide each other's DMA drains).
// Epilogue writes PARTIAL scores to spart[nh]; softmax sums the halves.
// ---------------------------------------------------------------------------
__global__ __launch_bounds__(256, 4) void main_k(const float* __restrict__ enc,
                                                 const ushort_t* __restrict__ Bt,
                                                 const float* __restrict__ dec,
                                                 const float* __restrict__ w2,
                                                 float* __restrict__ spart) {
  const int b  = blockIdx.y;
  const int l0 = blockIdx.x * 64;
  const int nh = blockIdx.z;             // n-half: cols nh*256 .. nh*256+255
  const int t  = threadIdx.x;            // 0..255
  const int wave = t >> 6, lane = t & 63;
  const int col = lane & 15, quad = lane >> 4;

  __shared__ ushort_t As[64 * 64];       // 8 KB  [m][k], XOR-swizzled 16B chunks
  __shared__ ushort_t Bs[256 * 64];      // 32 KB [n_local][k], XOR-swizzled

  floatx4 acc[4][4];
  #pragma unroll
  for (int mt = 0; mt < 4; mt++)
    #pragma unroll
    for (int nt = 0; nt < 4; nt++)
      acc[mt][nt] = (floatx4){0.f, 0.f, 0.f, 0.f};

  const float* arow = enc + (size_t)(b * L_SZ + l0) * E_SZ;

  // ---- A geometry: thread owns chunks t and t+256 (rows am0, am0+32) ----
  const int am0 = t >> 3, ac = t & 7;
  const int am1 = am0 + 32;
  const float* aptr0 = arow + am0 * E_SZ + ac * 8;
  const float* aptr1 = arow + am1 * E_SZ + ac * 8;
  ushort_t* awr0 = &As[am0 * 64 + ((ac ^ (am0 & 7)) << 3)];
  ushort_t* awr1 = &As[am1 * 64 + ((ac ^ (am1 & 7)) << 3)];

  // ---- B DMA geometry (round-2 exact, 256-row tile): slot s = wave*512+j*64+lane
  //      -> n_local = s>>3 = wave*64+j*8+(lane>>3), src chunk c = (s&7)^(n_local&7) ----
  const int bn0 = wave * 64 + (lane >> 3);
  const int bc0 = (lane & 7) ^ ((lane >> 3) & 7);
  const ushort_t* bptr0 = Bt + (size_t)(nh * 256 + bn0) * E_SZ + bc0 * 8;

  float4 pa0 = *(const float4*)aptr0;
  float4 pb0 = *(const float4*)(aptr0 + 4);
  float4 pa1 = *(const float4*)aptr1;
  float4 pb1 = *(const float4*)(aptr1 + 4);

  #pragma unroll 1
  for (int kw = 0; kw < 8; kw++) {
    __syncthreads();   // barrier1: previous window's LDS readers done
    // ---- stage A: cvt prefetched regs -> LDS (2 chunks) ----
    {
      union { short8 v; __hip_bfloat162 h[4]; } pk;
      pk.h[0] = __float22bfloat162_rn(make_float2(pa0.x, pa0.y));
      pk.h[1] = __float22bfloat162_rn(make_float2(pa0.z, pa0.w));
      pk.h[2] = __float22bfloat162_rn(make_float2(pb0.x, pb0.y));
      pk.h[3] = __float22bfloat162_rn(make_float2(pb0.z, pb0.w));
      *(short8*)awr0 = pk.v;
      pk.h[0] = __float22bfloat162_rn(make_float2(pa1.x, pa1.y));
      pk.h[1] = __float22bfloat162_rn(make_float2(pa1.z, pa1.w));
      pk.h[2] = __float22bfloat162_rn(make_float2(pb1.x, pb1.y));
      pk.h[3] = __float22bfloat162_rn(make_float2(pb1.z, pb1.w));
      *(short8*)awr1 = pk.v;
    }
    // ---- B: 8 async DMAs per wave ----
    const ushort_t* bp = bptr0 + kw * 64;
    #pragma unroll
    for (int j = 0; j < 8; j++)
      dma16(bp + j * 8 * E_SZ, &Bs[(wave * 512 + j * 64) * 8]);
    __syncthreads();   // barrier2: drains DMA (vmcnt) + ds_write (lgkmcnt)
    // ---- prefetch A for next window (latency hides under MFMA) ----
    if (kw < 7) {
      const float* ap0 = aptr0 + (kw + 1) * 64;
      const float* ap1 = aptr1 + (kw + 1) * 64;
      pa0 = *(const float4*)ap0;
      pb0 = *(const float4*)(ap0 + 4);
      pa1 = *(const float4*)ap1;
      pb1 = *(const float4*)(ap1 + 4);
    }
    // ---- MFMA: 2 k-steps of 32 ----
    #pragma unroll
    for (int ks = 0; ks < 2; ks++) {
      short8 af[4];
      #pragma unroll
      for (int mt = 0; mt < 4; mt++) {
        int m = mt * 16 + col;
        af[mt] = *(const short8*)&As[m * 64 + ((((ks << 2) + quad) ^ (m & 7)) << 3)];
      }
      #pragma unroll
      for (int nt = 0; nt < 4; nt++) {
        int nl = wave * 64 + nt * 16 + col;
        short8 bfr = *(const short8*)&Bs[nl * 64 + ((((ks << 2) + quad) ^ (nl & 7)) << 3)];
        #pragma unroll
        for (int mt = 0; mt < 4; mt++)
          acc[mt][nt] = __builtin_amdgcn_mfma_f32_16x16x32_bf16(af[mt], bfr, acc[mt][nt], 0, 0, 0);
      }
    }
  }

  // ---- epilogue: tanh(acc + dec) . w2, reduce over this WG's 256 n-cols ----
  // C/D: m = mt*16 + quad*4 + r, n_global = nh*256 + wave*64 + nt*16 + col
  const float* decb = dec + b * D_SZ + nh * 256;
  const float* w2b  = w2 + nh * 256;
  float sums[4][4];
  #pragma unroll
  for (int mt = 0; mt < 4; mt++)
    #pragma unroll
    for (int r = 0; r < 4; r++) sums[mt][r] = 0.f;
  #pragma unroll
  for (int nt = 0; nt < 4; nt++) {
    int nl = wave * 64 + nt * 16 + col;
    float dv = decb[nl];
    float wv = w2b[nl];
    #pragma unroll
    for (int mt = 0; mt < 4; mt++)
      #pragma unroll
      for (int r = 0; r < 4; r++)
        sums[mt][r] += fast_tanh(acc[mt][nt][r] + dv) * wv;
  }
  __syncthreads();                   // ALL waves done reading As (last MFMA)
  float* scf = (float*)&As[0];       // reuse As as 64-float partial-score row
  if (t < 64) scf[t] = 0.f;
  __syncthreads();                   // zero visible
  #pragma unroll
  for (int mt = 0; mt < 4; mt++) {
    #pragma unroll
    for (int r = 0; r < 4; r++) {
      float v = sums[mt][r];
      v += __shfl_xor(v, 1, 16);
      v += __shfl_xor(v, 2, 16);
      v += __shfl_xor(v, 4, 16);
      v += __shfl_xor(v, 8, 16);
      if (col == 0) atomicAdd(&scf[mt * 16 + quad * 4 + r], v);  // 4 waves/row
    }
  }
  __syncthreads();
  if (t < 64) spart[nh * (32 * L_SZ) + b * L_SZ + l0 + t] = scf[t];
}

// ---------------------------------------------------------------------------
// Softmax: one WG (1024 threads) per batch row; sums the two n-half partials.
// ---------------------------------------------------------------------------
__global__ __launch_bounds__(1024) void softmax_k(const float* __restrict__ sp,
                                                  float* __restrict__ out) {
  int b = blockIdx.x, t = threadIdx.x;
  int wave = t >> 6, lane = t & 63;
  __shared__ float redm[16], reds[16];
  const float* r0 = sp + b * L_SZ;
  const float* r1 = sp + 32 * L_SZ + b * L_SZ;
  float v0 = r0[t] + r1[t];
  float v1 = r0[t + 1024] + r1[t + 1024];
  float mx = fmaxf(v0, v1);
  #pragma unroll
  for (int off = 32; off >= 1; off >>= 1) mx = fmaxf(mx, __shfl_xor(mx, off, 64));
  if (lane == 0) redm[wave] = mx;
  __syncthreads();
  float m = redm[0];
  #pragma unroll
  for (int i = 1; i < 16; i++) m = fmaxf(m, redm[i]);
  v0 = __expf(v0 - m);
  v1 = __expf(v1 - m);
  float s = v0 + v1;
  #pragma unroll
  for (int off = 32; off >= 1; off >>= 1) s += __shfl_xor(s, off, 64);
  if (lane == 0) reds[wave] = s;
  __syncthreads();
  float sum = reds[0];
  #pragma unroll
  for (int i = 1; i < 16; i++) sum += reds[i];
  float inv = 1.0f / sum;
  out[b * L_SZ + t]        = v0 * inv;
  out[b * L_SZ + t + 1024] = v1 * inv;
}

extern "C" void kernel_launch(void* const* d_in, const int* in_sizes, int n_in,
                              void* d_out, int out_size, void* d_ws, size_t ws_size,
                              hipStream_t stream) {
  const float* d_hidden = (const float*)d_in[0];   // (32, 2, 512)
  const float* enc      = (const float*)d_in[1];   // (32, 2048, 512)
  const float* W1       = (const float*)d_in[2];   // (1536, 512)
  const float* b1       = (const float*)d_in[3];   // (512,)
  const float* w2       = (const float*)d_in[4];   // (512,)
  float* out = (float*)d_out;                      // (32, 2048)

  char* ws = (char*)d_ws;
  float*    dec = (float*)(ws + WS_DEC_OFF);
  ushort_t* Bt  = (ushort_t*)(ws + WS_BT_OFF);
  float*    sp  = (float*)(ws + WS_SP_OFF);

  prep_k<<<512, 256, 0, stream>>>(d_hidden, W1, b1, dec, Bt);
  main_k<<<dim3(32, 32, 2), 256, 0, stream>>>(enc, Bt, dec, w2, sp);
  softmax_k<<<32, 1024, 0, stream>>>(sp, out);
}